// Round 3
// baseline (997.848 us; speedup 1.0000x reference)
//
#include <hip/hip_runtime.h>

// Problem constants (match reference setup_inputs)
#define NN 100000
#define NE 600000
#define NG 256
#define HID 128
#define BN_EPS 1e-5f

#define SCAN_TILE 1024
#define NTILES ((NN + SCAN_TILE - 1) / SCAN_TILE)  // 98

// ---------------- histogram of dst (in-degree) ----------------

__global__ __launch_bounds__(256) void hist_kernel(const int* __restrict__ dst, int* __restrict__ cnt) {
    int e = blockIdx.x * blockDim.x + threadIdx.x;
    if (e < NE) atomicAdd(&cnt[dst[e]], 1);
}

__global__ __launch_bounds__(256) void dinv_kernel(const int* __restrict__ cnt, float* __restrict__ dinv) {
    int n = blockIdx.x * blockDim.x + threadIdx.x;
    if (n < NN) dinv[n] = rsqrtf((float)cnt[n] + 1.0f);
}

// ---------------- 2-level exclusive scan of cnt -> row_start ----------------

__global__ __launch_bounds__(256) void scan_a(const int* __restrict__ cnt, int* __restrict__ rs,
                                              int* __restrict__ tsum) {
    __shared__ int s[256];
    int t = threadIdx.x;
    int base = blockIdx.x * SCAN_TILE;
    int idx = base + t * 4;
    int v0 = (idx + 0 < NN) ? cnt[idx + 0] : 0;
    int v1 = (idx + 1 < NN) ? cnt[idx + 1] : 0;
    int v2 = (idx + 2 < NN) ? cnt[idx + 2] : 0;
    int v3 = (idx + 3 < NN) ? cnt[idx + 3] : 0;
    int local = v0 + v1 + v2 + v3;
    s[t] = local;
    __syncthreads();
    for (int off = 1; off < 256; off <<= 1) {
        int x = (t >= off) ? s[t - off] : 0;
        __syncthreads();
        s[t] += x;
        __syncthreads();
    }
    int pre = s[t] - local;  // exclusive prefix within tile
    if (t == 255) tsum[blockIdx.x] = s[255];
    if (idx + 0 < NN) rs[idx + 0] = pre; pre += v0;
    if (idx + 1 < NN) rs[idx + 1] = pre; pre += v1;
    if (idx + 2 < NN) rs[idx + 2] = pre; pre += v2;
    if (idx + 3 < NN) rs[idx + 3] = pre;
}

__global__ __launch_bounds__(128) void scan_b(int* __restrict__ tsum) {
    __shared__ int s[128];
    int t = threadIdx.x;
    int v = (t < NTILES) ? tsum[t] : 0;
    s[t] = v;
    __syncthreads();
    for (int off = 1; off < 128; off <<= 1) {
        int x = (t >= off) ? s[t - off] : 0;
        __syncthreads();
        s[t] += x;
        __syncthreads();
    }
    if (t < NTILES) tsum[t] = s[t] - v;  // exclusive
}

__global__ __launch_bounds__(256) void scan_c(int* __restrict__ rs, const int* __restrict__ tsum,
                                              int* __restrict__ cursor) {
    int t = threadIdx.x;
    int base = blockIdx.x * SCAN_TILE;
    int off = tsum[blockIdx.x];
    for (int k = 0; k < 4; k++) {
        int idx = base + t * 4 + k;
        if (idx < NN) {
            int v = rs[idx] + off;
            rs[idx] = v;
            cursor[idx] = v;
        }
    }
    if (blockIdx.x == 0 && t == 0) rs[NN] = NE;
}

// ---------------- bucket edges by dst ----------------

__global__ __launch_bounds__(256) void bucket_kernel(const int* __restrict__ src, const int* __restrict__ dst,
                                                     int* __restrict__ cursor, int* __restrict__ esrc) {
    int e = blockIdx.x * blockDim.x + threadIdx.x;
    if (e < NE) {
        int pos = atomicAdd(&cursor[dst[e]], 1);
        esrc[pos] = src[e];
    }
}

// ---------------- layer 0 fully fused: agg(x) -> @W0 -> +b -> BN -> ReLU ----------------
// Aggregation is linear, so agg(x W) == agg(x) W. Gather x (28 B/edge, not 512 B).
// Block 256 thr: phase 1 = 32 nodes x 8 thr aggregate x into LDS;
// phase 2 = 2 halves x 128 features, matmul 7->128 from LDS broadcast.

__global__ __launch_bounds__(256) void gcn0_fused(const float* __restrict__ x,
                                                  const int* __restrict__ rs,
                                                  const int* __restrict__ esrc,
                                                  const float* __restrict__ dinv,
                                                  const float* __restrict__ W,
                                                  const float* __restrict__ b,
                                                  const float* __restrict__ gamma,
                                                  const float* __restrict__ beta,
                                                  const float* __restrict__ mean,
                                                  const float* __restrict__ var,
                                                  float* __restrict__ out) {
    int t = threadIdx.x;
    int j = t & 127;
    float w[7];
#pragma unroll
    for (int k = 0; k < 7; k++) w[k] = W[k * HID + j];
    float bj = b[j];
    float scale = gamma[j] * rsqrtf(var[j] + BN_EPS);
    float mj = mean[j], bt = beta[j];
    __shared__ float aggs[32][8];
    int m = t >> 3, f = t & 7;          // phase-1 mapping
    int half = t >> 7;                   // phase-2 mapping
    for (int n0 = blockIdx.x * 32; n0 < NN; n0 += gridDim.x * 32) {
        int n = n0 + m;
        float acc = 0.f;
        if (n < NN && f < 7) {
            float di = dinv[n];
            acc = x[n * 7 + f] * di * di;
            int e0 = rs[n], e1 = rs[n + 1];
            for (int e = e0; e < e1; e++) {
                int s = esrc[e];
                acc = fmaf(x[s * 7 + f], dinv[s] * di, acc);
            }
        }
        aggs[m][f] = acc;
        __syncthreads();
        int m2end = half * 16 + 16;
        for (int m2 = half * 16; m2 < m2end; m2++) {
            int n2 = n0 + m2;
            if (n2 < NN) {
                float o = bj;
#pragma unroll
                for (int k = 0; k < 7; k++) o = fmaf(aggs[m2][k], w[k], o);
                out[(size_t)n2 * HID + j] = fmaxf(fmaf(o - mj, scale, bt), 0.f);
            }
        }
        __syncthreads();
    }
}

// ---------------- layers 1/2 fully fused ----------------
// out[n] = relu(BN( (sum_e h[src]*norm + h[n]*dinv^2) @ W + b ))
// 256 thr = 2 nodes; W column register-resident (128 VGPR); agg row via LDS.

__global__ __launch_bounds__(256) void gcn_fused(const float* __restrict__ h,
                                                 const int* __restrict__ rs,
                                                 const int* __restrict__ esrc,
                                                 const float* __restrict__ dinv,
                                                 const float* __restrict__ W,
                                                 const float* __restrict__ b,
                                                 const float* __restrict__ gamma,
                                                 const float* __restrict__ beta,
                                                 const float* __restrict__ mean,
                                                 const float* __restrict__ var,
                                                 float* __restrict__ out) {
    int j = threadIdx.x & 127;
    int half = threadIdx.x >> 7;
    float w[HID];
#pragma unroll
    for (int k = 0; k < HID; k++) w[k] = W[k * HID + j];
    float bj = b[j];
    float scale = gamma[j] * rsqrtf(var[j] + BN_EPS);
    float mj = mean[j], bt = beta[j];
    __shared__ float agg[2][HID];
    for (int n0 = blockIdx.x * 2; n0 < NN; n0 += gridDim.x * 2) {
        int n = n0 + half;  // NN is even; both nodes valid
        float di = dinv[n];
        float acc = h[(size_t)n * HID + j] * di * di;
        int e0 = rs[n], e1 = rs[n + 1];
        for (int e = e0; e < e1; e++) {
            int s = esrc[e];
            acc = fmaf(h[(size_t)s * HID + j], dinv[s] * di, acc);
        }
        agg[half][j] = acc;
        __syncthreads();
        float o = bj;
        const float4* a4 = (const float4*)agg[half];
#pragma unroll
        for (int k4 = 0; k4 < HID / 4; k4++) {
            float4 v = a4[k4];
            o = fmaf(v.x, w[4 * k4 + 0], o);
            o = fmaf(v.y, w[4 * k4 + 1], o);
            o = fmaf(v.z, w[4 * k4 + 2], o);
            o = fmaf(v.w, w[4 * k4 + 3], o);
        }
        out[(size_t)n * HID + j] = fmaxf(fmaf(o - mj, scale, bt), 0.f);
        __syncthreads();
    }
}

// ---------------- global mean pool (batch is sorted) ----------------

__global__ __launch_bounds__(128) void pool_kernel(const float* __restrict__ h,
                                                   const int* __restrict__ batch,
                                                   float* __restrict__ lig) {
    int g = blockIdx.x;
    int j = threadIdx.x;
    __shared__ int se[2];
    if (j < 2) {
        int target = g + j;
        int lo = 0, hi = NN;
        while (lo < hi) {
            int mid = (lo + hi) >> 1;
            if (batch[mid] < target) lo = mid + 1; else hi = mid;
        }
        se[j] = lo;
    }
    __syncthreads();
    int start = se[0], end = se[1];
    float acc = 0.f;
    for (int n = start; n < end; n++) acc += h[(size_t)n * HID + j];
    float cnt = (float)(end - start);
    lig[g * HID + j] = acc / fmaxf(cnt, 1.0f);
}

// ---------------- pocket MLP: 28 -> 64 -> 64 ----------------

__global__ __launch_bounds__(64) void pocket_kernel(const float* __restrict__ pocket,
                                                    const float* __restrict__ pw1,
                                                    const float* __restrict__ pb1,
                                                    const float* __restrict__ pw2,
                                                    const float* __restrict__ pb2,
                                                    float* __restrict__ p) {
    int j = threadIdx.x;
    __shared__ float t1[64];
    float acc = pb1[j];
    for (int k = 0; k < 28; k++) acc = fmaf(pocket[k], pw1[k * 64 + j], acc);
    t1[j] = fmaxf(acc, 0.f);
    __syncthreads();
    float acc2 = pb2[j];
    for (int k = 0; k < 64; k++) acc2 = fmaf(t1[k], pw2[k * 64 + j], acc2);
    p[j] = acc2;
}

// ---------------- classifier: concat(lig, p) -> 96 -> 1 ----------------

__global__ __launch_bounds__(96) void cls_kernel(const float* __restrict__ lig,
                                                 const float* __restrict__ p,
                                                 const float* __restrict__ cw1,
                                                 const float* __restrict__ cb1,
                                                 const float* __restrict__ cw2,
                                                 const float* __restrict__ cb2,
                                                 float* __restrict__ out) {
    int g = blockIdx.x;
    int j = threadIdx.x;
    __shared__ float emb[192];
    __shared__ float hid[96];
    for (int k = j; k < HID; k += 96) emb[k] = lig[g * HID + k];
    for (int k = j; k < 64; k += 96) emb[HID + k] = p[k];
    __syncthreads();
    float acc = cb1[j];
    for (int k = 0; k < 192; k++) acc = fmaf(emb[k], cw1[k * 96 + j], acc);
    hid[j] = fmaxf(acc, 0.f) * cw2[j];
    __syncthreads();
    if (j == 0) {
        float s = cb2[0];
        for (int k = 0; k < 96; k++) s += hid[k];
        out[g] = s;
    }
}

extern "C" void kernel_launch(void* const* d_in, const int* in_sizes, int n_in,
                              void* d_out, int out_size, void* d_ws, size_t ws_size,
                              hipStream_t stream) {
    const float* x        = (const float*)d_in[0];
    const int*   eidx     = (const int*)d_in[1];
    const int*   batch    = (const int*)d_in[2];
    const float* pocket   = (const float*)d_in[3];
    const float* W0 = (const float*)d_in[4];
    const float* b0 = (const float*)d_in[5];
    const float* W1 = (const float*)d_in[6];
    const float* b1 = (const float*)d_in[7];
    const float* W2 = (const float*)d_in[8];
    const float* b2 = (const float*)d_in[9];
    const float* bn_gamma = (const float*)d_in[10];
    const float* bn_beta  = (const float*)d_in[11];
    const float* bn_mean  = (const float*)d_in[12];
    const float* bn_var   = (const float*)d_in[13];
    const float* pw1 = (const float*)d_in[14]; const float* pb1 = (const float*)d_in[15];
    const float* pw2 = (const float*)d_in[16]; const float* pb2 = (const float*)d_in[17];
    const float* cw1 = (const float*)d_in[18]; const float* cb1 = (const float*)d_in[19];
    const float* cw2 = (const float*)d_in[20]; const float* cb2 = (const float*)d_in[21];
    float* out = (float*)d_out;

    // Workspace layout (4-byte units, A/B 16B-aligned):
    float* ws   = (float*)d_ws;
    float* dinv = ws;                                   // NN floats
    int*   cnt  = (int*)(ws + NN);                      // NN ints (hist, then cursor)
    int*   rs   = cnt + NN;                             // NN+1 ints (row_start)
    int*   tsum = rs + NN + 1;                          // 128 ints
    int*   esrc = tsum + 128;                           // NE ints
    size_t head = (size_t)NN + NN + (NN + 1) + 128 + NE;
    head = (head + 3) & ~(size_t)3;                     // 16B align
    float* A    = ws + head;                            // NN*HID
    float* B    = A + (size_t)NN * HID;                 // NN*HID
    float* lig  = B + (size_t)NN * HID;                 // NG*HID
    float* pv   = lig + (size_t)NG * HID;               // 64

    const int* srcp = eidx;
    const int* dstp = eidx + NE;

    // ---- build CSR (by dst) + dinv ----
    hipMemsetAsync(cnt, 0, NN * sizeof(int), stream);
    hist_kernel<<<(NE + 255) / 256, 256, 0, stream>>>(dstp, cnt);
    dinv_kernel<<<(NN + 255) / 256, 256, 0, stream>>>(cnt, dinv);
    scan_a<<<NTILES, 256, 0, stream>>>(cnt, rs, tsum);
    scan_b<<<1, 128, 0, stream>>>(tsum);
    scan_c<<<NTILES, 256, 0, stream>>>(rs, tsum, cnt);  // cnt becomes cursor
    bucket_kernel<<<(NE + 255) / 256, 256, 0, stream>>>(srcp, dstp, cnt, esrc);

    // layer 0: x -> A  (aggregate-then-transform, fused BN+ReLU)
    gcn0_fused<<<1024, 256, 0, stream>>>(x, rs, esrc, dinv, W0, b0,
                                         bn_gamma + 0 * HID, bn_beta + 0 * HID,
                                         bn_mean + 0 * HID, bn_var + 0 * HID, A);
    // layer 1: A -> B
    gcn_fused<<<2048, 256, 0, stream>>>(A, rs, esrc, dinv, W1, b1,
                                        bn_gamma + 1 * HID, bn_beta + 1 * HID,
                                        bn_mean + 1 * HID, bn_var + 1 * HID, B);
    // layer 2: B -> A
    gcn_fused<<<2048, 256, 0, stream>>>(B, rs, esrc, dinv, W2, b2,
                                        bn_gamma + 2 * HID, bn_beta + 2 * HID,
                                        bn_mean + 2 * HID, bn_var + 2 * HID, A);

    // pool -> lig
    pool_kernel<<<NG, 128, 0, stream>>>(A, batch, lig);
    // pocket MLP
    pocket_kernel<<<1, 64, 0, stream>>>(pocket, pw1, pb1, pw2, pb2, pv);
    // classifier
    cls_kernel<<<NG, 96, 0, stream>>>(lig, pv, cw1, cb1, cw2, cb2, out);
}

// Round 4
// 560.342 us; speedup vs baseline: 1.7808x; 1.7808x over previous
//
#include <hip/hip_runtime.h>

// Problem constants (match reference setup_inputs)
#define NN 100000
#define NE 600000
#define NG 256
#define HID 128
#define BN_EPS 1e-5f

#define SCAN_TILE 1024
#define NTILES ((NN + SCAN_TILE - 1) / SCAN_TILE)  // 98

// ---------------- histogram of dst (in-degree) ----------------

__global__ __launch_bounds__(256) void hist_kernel(const int* __restrict__ dst, int* __restrict__ cnt) {
    int e = blockIdx.x * blockDim.x + threadIdx.x;
    if (e < NE) atomicAdd(&cnt[dst[e]], 1);
}

__global__ __launch_bounds__(256) void dinv_kernel(const int* __restrict__ cnt, float* __restrict__ dinv) {
    int n = blockIdx.x * blockDim.x + threadIdx.x;
    if (n < NN) dinv[n] = rsqrtf((float)cnt[n] + 1.0f);
}

// ---------------- 2-level exclusive scan of cnt -> row_start ----------------

__global__ __launch_bounds__(256) void scan_a(const int* __restrict__ cnt, int* __restrict__ rs,
                                              int* __restrict__ tsum) {
    __shared__ int s[256];
    int t = threadIdx.x;
    int base = blockIdx.x * SCAN_TILE;
    int idx = base + t * 4;
    int v0 = (idx + 0 < NN) ? cnt[idx + 0] : 0;
    int v1 = (idx + 1 < NN) ? cnt[idx + 1] : 0;
    int v2 = (idx + 2 < NN) ? cnt[idx + 2] : 0;
    int v3 = (idx + 3 < NN) ? cnt[idx + 3] : 0;
    int local = v0 + v1 + v2 + v3;
    s[t] = local;
    __syncthreads();
    for (int off = 1; off < 256; off <<= 1) {
        int x = (t >= off) ? s[t - off] : 0;
        __syncthreads();
        s[t] += x;
        __syncthreads();
    }
    int pre = s[t] - local;  // exclusive prefix within tile
    if (t == 255) tsum[blockIdx.x] = s[255];
    if (idx + 0 < NN) rs[idx + 0] = pre; pre += v0;
    if (idx + 1 < NN) rs[idx + 1] = pre; pre += v1;
    if (idx + 2 < NN) rs[idx + 2] = pre; pre += v2;
    if (idx + 3 < NN) rs[idx + 3] = pre;
}

__global__ __launch_bounds__(128) void scan_b(int* __restrict__ tsum) {
    __shared__ int s[128];
    int t = threadIdx.x;
    int v = (t < NTILES) ? tsum[t] : 0;
    s[t] = v;
    __syncthreads();
    for (int off = 1; off < 128; off <<= 1) {
        int x = (t >= off) ? s[t - off] : 0;
        __syncthreads();
        s[t] += x;
        __syncthreads();
    }
    if (t < NTILES) tsum[t] = s[t] - v;  // exclusive
}

__global__ __launch_bounds__(256) void scan_c(int* __restrict__ rs, const int* __restrict__ tsum,
                                              int* __restrict__ cursor) {
    int t = threadIdx.x;
    int base = blockIdx.x * SCAN_TILE;
    int off = tsum[blockIdx.x];
    for (int k = 0; k < 4; k++) {
        int idx = base + t * 4 + k;
        if (idx < NN) {
            int v = rs[idx] + off;
            rs[idx] = v;
            cursor[idx] = v;
        }
    }
    if (blockIdx.x == 0 && t == 0) rs[NN] = NE;
}

// ---------------- bucket edges by dst (also precompute edge weights) ----------------

__global__ __launch_bounds__(256) void bucket_kernel(const int* __restrict__ src, const int* __restrict__ dst,
                                                     const float* __restrict__ dinv,
                                                     int* __restrict__ cursor,
                                                     int* __restrict__ esrc, float* __restrict__ ewt) {
    int e = blockIdx.x * blockDim.x + threadIdx.x;
    if (e < NE) {
        int s = src[e], d = dst[e];
        int pos = atomicAdd(&cursor[d], 1);
        esrc[pos] = s;
        ewt[pos] = dinv[s] * dinv[d];
    }
}

// ---------------- layer 0 part A: aggregate raw x (7-dim) -> xa [NN,8] ----------------
// 8 threads per node (7 active). Tiny gather payload: 28 B/edge.

__global__ __launch_bounds__(256) void xagg_kernel(const float* __restrict__ x,
                                                   const int* __restrict__ rs,
                                                   const int* __restrict__ esrc,
                                                   const float* __restrict__ ewt,
                                                   const float* __restrict__ dinv,
                                                   float* __restrict__ xa) {
    int t = blockIdx.x * blockDim.x + threadIdx.x;
    int f = t & 7;
    int n = t >> 3;
    if (n >= NN) return;
    float acc = 0.f;
    if (f < 7) {
        float di = dinv[n];
        acc = x[n * 7 + f] * di * di;
        int e0 = rs[n], e1 = rs[n + 1];
        int e = e0;
        for (; e + 1 < e1; e += 2) {
            int s0 = esrc[e], s1 = esrc[e + 1];
            float w0 = ewt[e], w1 = ewt[e + 1];
            float a0 = x[s0 * 7 + f];
            float a1 = x[s1 * 7 + f];
            acc = fmaf(a0, w0, acc);
            acc = fmaf(a1, w1, acc);
        }
        if (e < e1) acc = fmaf(x[esrc[e] * 7 + f], ewt[e], acc);
    }
    xa[n * 8 + f] = acc;
}

// ---------------- layer 0 part B: xa @ W0 + b -> BN -> ReLU -> out ----------------
// NN % 32 == 0. 256 threads: stage 32 nodes x 8 feats, each half computes 16 nodes.

__global__ __launch_bounds__(256) void l0_transform(const float* __restrict__ xa,
                                                    const float* __restrict__ W,
                                                    const float* __restrict__ b,
                                                    const float* __restrict__ gamma,
                                                    const float* __restrict__ beta,
                                                    const float* __restrict__ mean,
                                                    const float* __restrict__ var,
                                                    float* __restrict__ out) {
    int j = threadIdx.x & 127;
    int half = threadIdx.x >> 7;
    float w[7];
#pragma unroll
    for (int k = 0; k < 7; k++) w[k] = W[k * HID + j];
    float bj = b[j];
    float scale = gamma[j] * rsqrtf(var[j] + BN_EPS);
    float mj = mean[j], bt = beta[j];
    __shared__ float s[32][8];
    int r = threadIdx.x >> 3, f = threadIdx.x & 7;
    for (int n0 = blockIdx.x * 32; n0 < NN; n0 += gridDim.x * 32) {
        __syncthreads();
        s[r][f] = xa[(n0 + r) * 8 + f];
        __syncthreads();
        int mend = half * 16 + 16;
        for (int m = half * 16; m < mend; m++) {
            float o = bj;
#pragma unroll
            for (int k = 0; k < 7; k++) o = fmaf(s[m][k], w[k], o);
            out[(size_t)(n0 + m) * HID + j] = fmaxf(fmaf(o - mj, scale, bt), 0.f);
        }
    }
}

// ---------------- layers 1/2 matmul: h [NN,128] @ W [128,128] -> hl ----------------
// 256 threads, 8 rows per barrier pair, 4 accumulators/thread. NN % 8 == 0.

__global__ __launch_bounds__(256) void gcn_mm128(const float* __restrict__ hin,
                                                 const float* __restrict__ W,
                                                 float* __restrict__ hl) {
    int j = threadIdx.x & 127;
    int half = threadIdx.x >> 7;
    float w[HID];
#pragma unroll
    for (int k = 0; k < HID; k++) w[k] = W[k * HID + j];
    __shared__ float hs[8][HID];
    int r = threadIdx.x >> 5;        // 0..7 staging row
    int c4 = threadIdx.x & 31;       // float4 index within row
    for (int n0 = blockIdx.x * 8; n0 < NN; n0 += gridDim.x * 8) {
        float4 v = ((const float4*)hin)[(size_t)(n0 + r) * 32 + c4];
        __syncthreads();
        ((float4*)hs[r])[c4] = v;
        __syncthreads();
        int rb = half * 4;
        float acc0 = 0.f, acc1 = 0.f, acc2 = 0.f, acc3 = 0.f;
        const float4* a0 = (const float4*)hs[rb + 0];
        const float4* a1 = (const float4*)hs[rb + 1];
        const float4* a2 = (const float4*)hs[rb + 2];
        const float4* a3 = (const float4*)hs[rb + 3];
#pragma unroll
        for (int k4 = 0; k4 < HID / 4; k4++) {
            float4 x0 = a0[k4], x1 = a1[k4], x2 = a2[k4], x3 = a3[k4];
            float w0 = w[4 * k4 + 0], w1 = w[4 * k4 + 1], w2 = w[4 * k4 + 2], w3 = w[4 * k4 + 3];
            acc0 = fmaf(x0.x, w0, acc0); acc0 = fmaf(x0.y, w1, acc0);
            acc0 = fmaf(x0.z, w2, acc0); acc0 = fmaf(x0.w, w3, acc0);
            acc1 = fmaf(x1.x, w0, acc1); acc1 = fmaf(x1.y, w1, acc1);
            acc1 = fmaf(x1.z, w2, acc1); acc1 = fmaf(x1.w, w3, acc1);
            acc2 = fmaf(x2.x, w0, acc2); acc2 = fmaf(x2.y, w1, acc2);
            acc2 = fmaf(x2.z, w2, acc2); acc2 = fmaf(x2.w, w3, acc2);
            acc3 = fmaf(x3.x, w0, acc3); acc3 = fmaf(x3.y, w1, acc3);
            acc3 = fmaf(x3.z, w2, acc3); acc3 = fmaf(x3.w, w3, acc3);
        }
        hl[(size_t)(n0 + rb + 0) * HID + j] = acc0;
        hl[(size_t)(n0 + rb + 1) * HID + j] = acc1;
        hl[(size_t)(n0 + rb + 2) * HID + j] = acc2;
        hl[(size_t)(n0 + rb + 3) * HID + j] = acc3;
    }
}

// ---------------- gather-aggregate + self-loop + bias + BN + ReLU ----------------
// 32 threads/node, float4 per thread, 2x unrolled edge loop, precomputed weights.

__global__ __launch_bounds__(256) void gather_bn(const float* __restrict__ hl,
                                                 const int* __restrict__ rs,
                                                 const int* __restrict__ esrc,
                                                 const float* __restrict__ ewt,
                                                 const float* __restrict__ dinv,
                                                 const float* __restrict__ b,
                                                 const float* __restrict__ gamma,
                                                 const float* __restrict__ beta,
                                                 const float* __restrict__ mean,
                                                 const float* __restrict__ var,
                                                 float* __restrict__ out) {
    int t = blockIdx.x * blockDim.x + threadIdx.x;
    int lane = t & 31;
    int n = t >> 5;
    if (n >= NN) return;
    const float4* hl4 = (const float4*)hl;
    float di = dinv[n];
    float4 self = hl4[(size_t)n * 32 + lane];
    float4 bb = ((const float4*)b)[lane];
    float dsq = di * di;
    float4 acc;
    acc.x = fmaf(self.x, dsq, bb.x);
    acc.y = fmaf(self.y, dsq, bb.y);
    acc.z = fmaf(self.z, dsq, bb.z);
    acc.w = fmaf(self.w, dsq, bb.w);
    int e0 = rs[n], e1 = rs[n + 1];
    int e = e0;
    for (; e + 1 < e1; e += 2) {
        int s0 = esrc[e], s1 = esrc[e + 1];
        float w0 = ewt[e], w1 = ewt[e + 1];
        float4 v0 = hl4[(size_t)s0 * 32 + lane];
        float4 v1 = hl4[(size_t)s1 * 32 + lane];
        acc.x = fmaf(v0.x, w0, acc.x); acc.y = fmaf(v0.y, w0, acc.y);
        acc.z = fmaf(v0.z, w0, acc.z); acc.w = fmaf(v0.w, w0, acc.w);
        acc.x = fmaf(v1.x, w1, acc.x); acc.y = fmaf(v1.y, w1, acc.y);
        acc.z = fmaf(v1.z, w1, acc.z); acc.w = fmaf(v1.w, w1, acc.w);
    }
    if (e < e1) {
        int s0 = esrc[e];
        float w0 = ewt[e];
        float4 v0 = hl4[(size_t)s0 * 32 + lane];
        acc.x = fmaf(v0.x, w0, acc.x); acc.y = fmaf(v0.y, w0, acc.y);
        acc.z = fmaf(v0.z, w0, acc.z); acc.w = fmaf(v0.w, w0, acc.w);
    }
    float4 ga = ((const float4*)gamma)[lane];
    float4 be = ((const float4*)beta)[lane];
    float4 me = ((const float4*)mean)[lane];
    float4 va = ((const float4*)var)[lane];
    float4 o;
    o.x = fmaxf(fmaf(acc.x - me.x, ga.x * rsqrtf(va.x + BN_EPS), be.x), 0.f);
    o.y = fmaxf(fmaf(acc.y - me.y, ga.y * rsqrtf(va.y + BN_EPS), be.y), 0.f);
    o.z = fmaxf(fmaf(acc.z - me.z, ga.z * rsqrtf(va.z + BN_EPS), be.z), 0.f);
    o.w = fmaxf(fmaf(acc.w - me.w, ga.w * rsqrtf(va.w + BN_EPS), be.w), 0.f);
    ((float4*)out)[(size_t)n * 32 + lane] = o;
}

// ---------------- global mean pool (batch is sorted) ----------------

__global__ __launch_bounds__(128) void pool_kernel(const float* __restrict__ h,
                                                   const int* __restrict__ batch,
                                                   float* __restrict__ lig) {
    int g = blockIdx.x;
    int j = threadIdx.x;
    __shared__ int se[2];
    if (j < 2) {
        int target = g + j;
        int lo = 0, hi = NN;
        while (lo < hi) {
            int mid = (lo + hi) >> 1;
            if (batch[mid] < target) lo = mid + 1; else hi = mid;
        }
        se[j] = lo;
    }
    __syncthreads();
    int start = se[0], end = se[1];
    float acc = 0.f;
    for (int n = start; n < end; n++) acc += h[(size_t)n * HID + j];
    float cnt = (float)(end - start);
    lig[g * HID + j] = acc / fmaxf(cnt, 1.0f);
}

// ---------------- pocket MLP: 28 -> 64 -> 64 ----------------

__global__ __launch_bounds__(64) void pocket_kernel(const float* __restrict__ pocket,
                                                    const float* __restrict__ pw1,
                                                    const float* __restrict__ pb1,
                                                    const float* __restrict__ pw2,
                                                    const float* __restrict__ pb2,
                                                    float* __restrict__ p) {
    int j = threadIdx.x;
    __shared__ float t1[64];
    float acc = pb1[j];
    for (int k = 0; k < 28; k++) acc = fmaf(pocket[k], pw1[k * 64 + j], acc);
    t1[j] = fmaxf(acc, 0.f);
    __syncthreads();
    float acc2 = pb2[j];
    for (int k = 0; k < 64; k++) acc2 = fmaf(t1[k], pw2[k * 64 + j], acc2);
    p[j] = acc2;
}

// ---------------- classifier: concat(lig, p) -> 96 -> 1 ----------------

__global__ __launch_bounds__(96) void cls_kernel(const float* __restrict__ lig,
                                                 const float* __restrict__ p,
                                                 const float* __restrict__ cw1,
                                                 const float* __restrict__ cb1,
                                                 const float* __restrict__ cw2,
                                                 const float* __restrict__ cb2,
                                                 float* __restrict__ out) {
    int g = blockIdx.x;
    int j = threadIdx.x;
    __shared__ float emb[192];
    __shared__ float hid[96];
    for (int k = j; k < HID; k += 96) emb[k] = lig[g * HID + k];
    for (int k = j; k < 64; k += 96) emb[HID + k] = p[k];
    __syncthreads();
    float acc = cb1[j];
    for (int k = 0; k < 192; k++) acc = fmaf(emb[k], cw1[k * 96 + j], acc);
    hid[j] = fmaxf(acc, 0.f) * cw2[j];
    __syncthreads();
    if (j == 0) {
        float s = cb2[0];
        for (int k = 0; k < 96; k++) s += hid[k];
        out[g] = s;
    }
}

extern "C" void kernel_launch(void* const* d_in, const int* in_sizes, int n_in,
                              void* d_out, int out_size, void* d_ws, size_t ws_size,
                              hipStream_t stream) {
    const float* x        = (const float*)d_in[0];
    const int*   eidx     = (const int*)d_in[1];
    const int*   batch    = (const int*)d_in[2];
    const float* pocket   = (const float*)d_in[3];
    const float* W0 = (const float*)d_in[4];
    const float* b0 = (const float*)d_in[5];
    const float* W1 = (const float*)d_in[6];
    const float* b1 = (const float*)d_in[7];
    const float* W2 = (const float*)d_in[8];
    const float* b2 = (const float*)d_in[9];
    const float* bn_gamma = (const float*)d_in[10];
    const float* bn_beta  = (const float*)d_in[11];
    const float* bn_mean  = (const float*)d_in[12];
    const float* bn_var   = (const float*)d_in[13];
    const float* pw1 = (const float*)d_in[14]; const float* pb1 = (const float*)d_in[15];
    const float* pw2 = (const float*)d_in[16]; const float* pb2 = (const float*)d_in[17];
    const float* cw1 = (const float*)d_in[18]; const float* cb1 = (const float*)d_in[19];
    const float* cw2 = (const float*)d_in[20]; const float* cb2 = (const float*)d_in[21];
    float* out = (float*)d_out;

    // Workspace layout (4-byte units, A/B 16B-aligned):
    float* ws   = (float*)d_ws;
    float* dinv = ws;                                   // NN
    int*   cnt  = (int*)(ws + NN);                      // NN (hist, then cursor)
    int*   rs   = cnt + NN;                             // NN+1
    int*   tsum = rs + NN + 1;                          // 128
    int*   esrc = tsum + 128;                           // NE
    float* ewt  = (float*)(esrc + NE);                  // NE
    float* xa   = ewt + NE;                             // NN*8
    size_t head = (size_t)NN * 2 + (NN + 1) + 128 + (size_t)NE * 2 + (size_t)NN * 8;
    head = (head + 3) & ~(size_t)3;                     // 16B align
    float* A    = ws + head;                            // NN*HID
    float* B    = A + (size_t)NN * HID;                 // NN*HID
    float* lig  = B + (size_t)NN * HID;                 // NG*HID
    float* pv   = lig + (size_t)NG * HID;               // 64

    const int* srcp = eidx;
    const int* dstp = eidx + NE;

    // ---- build CSR (by dst) + dinv + edge weights ----
    hipMemsetAsync(cnt, 0, NN * sizeof(int), stream);
    hist_kernel<<<(NE + 255) / 256, 256, 0, stream>>>(dstp, cnt);
    dinv_kernel<<<(NN + 255) / 256, 256, 0, stream>>>(cnt, dinv);
    scan_a<<<NTILES, 256, 0, stream>>>(cnt, rs, tsum);
    scan_b<<<1, 128, 0, stream>>>(tsum);
    scan_c<<<NTILES, 256, 0, stream>>>(rs, tsum, cnt);  // cnt becomes cursor
    bucket_kernel<<<(NE + 255) / 256, 256, 0, stream>>>(srcp, dstp, dinv, cnt, esrc, ewt);

    // ---- layer 0: aggregate x, then transform (A = relu(bn(agg(x) @ W0 + b0))) ----
    xagg_kernel<<<(NN * 8 + 255) / 256, 256, 0, stream>>>(x, rs, esrc, ewt, dinv, xa);
    l0_transform<<<2048, 256, 0, stream>>>(xa, W0, b0,
                                           bn_gamma + 0 * HID, bn_beta + 0 * HID,
                                           bn_mean + 0 * HID, bn_var + 0 * HID, A);
    // ---- layer 1: A -> B(hl) -> A'? no: mm A->B, gather B->A... keep ping-pong ----
    gcn_mm128<<<2048, 256, 0, stream>>>(A, W1, B);
    gather_bn<<<(NN * 32 + 255) / 256, 256, 0, stream>>>(B, rs, esrc, ewt, dinv, b1,
                                                         bn_gamma + 1 * HID, bn_beta + 1 * HID,
                                                         bn_mean + 1 * HID, bn_var + 1 * HID, A);
    // ---- layer 2 ----
    gcn_mm128<<<2048, 256, 0, stream>>>(A, W2, B);
    gather_bn<<<(NN * 32 + 255) / 256, 256, 0, stream>>>(B, rs, esrc, ewt, dinv, b2,
                                                         bn_gamma + 2 * HID, bn_beta + 2 * HID,
                                                         bn_mean + 2 * HID, bn_var + 2 * HID, A);

    // pool -> lig
    pool_kernel<<<NG, 128, 0, stream>>>(A, batch, lig);
    // pocket MLP
    pocket_kernel<<<1, 64, 0, stream>>>(pocket, pw1, pb1, pw2, pb2, pv);
    // classifier
    cls_kernel<<<NG, 96, 0, stream>>>(lig, pv, cw1, cb1, cw2, cb2, out);
}

// Round 5
// 461.557 us; speedup vs baseline: 2.1619x; 1.2140x over previous
//
#include <hip/hip_runtime.h>

// Problem constants (match reference setup_inputs)
#define NN 100000
#define NE 600000
#define NG 256
#define HID 128
#define BN_EPS 1e-5f

#define SCAN_TILE 1024
#define NTILES ((NN + SCAN_TILE - 1) / SCAN_TILE)  // 98

// ---------------- histogram of dst (in-degree) ----------------

__global__ __launch_bounds__(256) void hist_kernel(const int* __restrict__ dst, int* __restrict__ cnt) {
    int e = blockIdx.x * blockDim.x + threadIdx.x;
    if (e < NE) atomicAdd(&cnt[dst[e]], 1);
}

__global__ __launch_bounds__(256) void dinv_kernel(const int* __restrict__ cnt, float* __restrict__ dinv) {
    int n = blockIdx.x * blockDim.x + threadIdx.x;
    if (n < NN) dinv[n] = rsqrtf((float)cnt[n] + 1.0f);
}

// ---------------- 2-level exclusive scan of cnt -> row_start ----------------

__global__ __launch_bounds__(256) void scan_a(const int* __restrict__ cnt, int* __restrict__ rs,
                                              int* __restrict__ tsum) {
    __shared__ int s[256];
    int t = threadIdx.x;
    int base = blockIdx.x * SCAN_TILE;
    int idx = base + t * 4;
    int v0 = (idx + 0 < NN) ? cnt[idx + 0] : 0;
    int v1 = (idx + 1 < NN) ? cnt[idx + 1] : 0;
    int v2 = (idx + 2 < NN) ? cnt[idx + 2] : 0;
    int v3 = (idx + 3 < NN) ? cnt[idx + 3] : 0;
    int local = v0 + v1 + v2 + v3;
    s[t] = local;
    __syncthreads();
    for (int off = 1; off < 256; off <<= 1) {
        int x = (t >= off) ? s[t - off] : 0;
        __syncthreads();
        s[t] += x;
        __syncthreads();
    }
    int pre = s[t] - local;  // exclusive prefix within tile
    if (t == 255) tsum[blockIdx.x] = s[255];
    if (idx + 0 < NN) rs[idx + 0] = pre; pre += v0;
    if (idx + 1 < NN) rs[idx + 1] = pre; pre += v1;
    if (idx + 2 < NN) rs[idx + 2] = pre; pre += v2;
    if (idx + 3 < NN) rs[idx + 3] = pre;
}

__global__ __launch_bounds__(128) void scan_b(int* __restrict__ tsum) {
    __shared__ int s[128];
    int t = threadIdx.x;
    int v = (t < NTILES) ? tsum[t] : 0;
    s[t] = v;
    __syncthreads();
    for (int off = 1; off < 128; off <<= 1) {
        int x = (t >= off) ? s[t - off] : 0;
        __syncthreads();
        s[t] += x;
        __syncthreads();
    }
    if (t < NTILES) tsum[t] = s[t] - v;  // exclusive
}

__global__ __launch_bounds__(256) void scan_c(int* __restrict__ rs, const int* __restrict__ tsum,
                                              int* __restrict__ cursor) {
    int t = threadIdx.x;
    int base = blockIdx.x * SCAN_TILE;
    int off = tsum[blockIdx.x];
    for (int k = 0; k < 4; k++) {
        int idx = base + t * 4 + k;
        if (idx < NN) {
            int v = rs[idx] + off;
            rs[idx] = v;
            cursor[idx] = v;
        }
    }
    if (blockIdx.x == 0 && t == 0) rs[NN] = NE;
}

// ---------------- bucket edges by dst (also precompute edge weights) ----------------

__global__ __launch_bounds__(256) void bucket_kernel(const int* __restrict__ src, const int* __restrict__ dst,
                                                     const float* __restrict__ dinv,
                                                     int* __restrict__ cursor,
                                                     int* __restrict__ esrc, float* __restrict__ ewt) {
    int e = blockIdx.x * blockDim.x + threadIdx.x;
    if (e < NE) {
        int s = src[e], d = dst[e];
        int pos = atomicAdd(&cursor[d], 1);
        esrc[pos] = s;
        ewt[pos] = dinv[s] * dinv[d];
    }
}

// ---------------- layer 0 part A: aggregate raw x (7-dim) -> xa [NN,8] ----------------

__global__ __launch_bounds__(256) void xagg_kernel(const float* __restrict__ x,
                                                   const int* __restrict__ rs,
                                                   const int* __restrict__ esrc,
                                                   const float* __restrict__ ewt,
                                                   const float* __restrict__ dinv,
                                                   float* __restrict__ xa) {
    int t = blockIdx.x * blockDim.x + threadIdx.x;
    int f = t & 7;
    int n = t >> 3;
    if (n >= NN) return;
    float acc = 0.f;
    if (f < 7) {
        float di = dinv[n];
        acc = x[n * 7 + f] * di * di;
        int e0 = rs[n], e1 = rs[n + 1];
        int e = e0;
        for (; e + 1 < e1; e += 2) {
            int s0 = esrc[e], s1 = esrc[e + 1];
            float w0 = ewt[e], w1 = ewt[e + 1];
            float a0 = x[s0 * 7 + f];
            float a1 = x[s1 * 7 + f];
            acc = fmaf(a0, w0, acc);
            acc = fmaf(a1, w1, acc);
        }
        if (e < e1) acc = fmaf(x[esrc[e] * 7 + f], ewt[e], acc);
    }
    xa[n * 8 + f] = acc;
}

// ---------------- layer 0 part B: xa @ W0 + b -> BN -> ReLU -> out ----------------

__global__ __launch_bounds__(256) void l0_transform(const float* __restrict__ xa,
                                                    const float* __restrict__ W,
                                                    const float* __restrict__ b,
                                                    const float* __restrict__ gamma,
                                                    const float* __restrict__ beta,
                                                    const float* __restrict__ mean,
                                                    const float* __restrict__ var,
                                                    float* __restrict__ out) {
    int j = threadIdx.x & 127;
    int half = threadIdx.x >> 7;
    float w[7];
#pragma unroll
    for (int k = 0; k < 7; k++) w[k] = W[k * HID + j];
    float bj = b[j];
    float scale = gamma[j] * rsqrtf(var[j] + BN_EPS);
    float mj = mean[j], bt = beta[j];
    __shared__ float s[32][8];
    int r = threadIdx.x >> 3, f = threadIdx.x & 7;
    for (int n0 = blockIdx.x * 32; n0 < NN; n0 += gridDim.x * 32) {
        __syncthreads();
        s[r][f] = xa[(n0 + r) * 8 + f];
        __syncthreads();
        int mend = half * 16 + 16;
        for (int m = half * 16; m < mend; m++) {
            float o = bj;
#pragma unroll
            for (int k = 0; k < 7; k++) o = fmaf(s[m][k], w[k], o);
            out[(size_t)(n0 + m) * HID + j] = fmaxf(fmaf(o - mj, scale, bt), 0.f);
        }
    }
}

// ---------------- layers 1/2 matmul: h [NN,128] @ W [128,128] -> hl ----------------

__global__ __launch_bounds__(256) void gcn_mm128(const float* __restrict__ hin,
                                                 const float* __restrict__ W,
                                                 float* __restrict__ hl) {
    int j = threadIdx.x & 127;
    int half = threadIdx.x >> 7;
    float w[HID];
#pragma unroll
    for (int k = 0; k < HID; k++) w[k] = W[k * HID + j];
    __shared__ float hs[8][HID];
    int r = threadIdx.x >> 5;        // 0..7 staging row
    int c4 = threadIdx.x & 31;       // float4 index within row
    for (int n0 = blockIdx.x * 8; n0 < NN; n0 += gridDim.x * 8) {
        float4 v = ((const float4*)hin)[(size_t)(n0 + r) * 32 + c4];
        __syncthreads();
        ((float4*)hs[r])[c4] = v;
        __syncthreads();
        int rb = half * 4;
        float acc0 = 0.f, acc1 = 0.f, acc2 = 0.f, acc3 = 0.f;
        const float4* a0 = (const float4*)hs[rb + 0];
        const float4* a1 = (const float4*)hs[rb + 1];
        const float4* a2 = (const float4*)hs[rb + 2];
        const float4* a3 = (const float4*)hs[rb + 3];
#pragma unroll
        for (int k4 = 0; k4 < HID / 4; k4++) {
            float4 x0 = a0[k4], x1 = a1[k4], x2 = a2[k4], x3 = a3[k4];
            float w0 = w[4 * k4 + 0], w1 = w[4 * k4 + 1], w2 = w[4 * k4 + 2], w3 = w[4 * k4 + 3];
            acc0 = fmaf(x0.x, w0, acc0); acc0 = fmaf(x0.y, w1, acc0);
            acc0 = fmaf(x0.z, w2, acc0); acc0 = fmaf(x0.w, w3, acc0);
            acc1 = fmaf(x1.x, w0, acc1); acc1 = fmaf(x1.y, w1, acc1);
            acc1 = fmaf(x1.z, w2, acc1); acc1 = fmaf(x1.w, w3, acc1);
            acc2 = fmaf(x2.x, w0, acc2); acc2 = fmaf(x2.y, w1, acc2);
            acc2 = fmaf(x2.z, w2, acc2); acc2 = fmaf(x2.w, w3, acc2);
            acc3 = fmaf(x3.x, w0, acc3); acc3 = fmaf(x3.y, w1, acc3);
            acc3 = fmaf(x3.z, w2, acc3); acc3 = fmaf(x3.w, w3, acc3);
        }
        hl[(size_t)(n0 + rb + 0) * HID + j] = acc0;
        hl[(size_t)(n0 + rb + 1) * HID + j] = acc1;
        hl[(size_t)(n0 + rb + 2) * HID + j] = acc2;
        hl[(size_t)(n0 + rb + 3) * HID + j] = acc3;
    }
}

// ---------------- gather-aggregate + self-loop + bias + BN + ReLU ----------------

__global__ __launch_bounds__(256) void gather_bn(const float* __restrict__ hl,
                                                 const int* __restrict__ rs,
                                                 const int* __restrict__ esrc,
                                                 const float* __restrict__ ewt,
                                                 const float* __restrict__ dinv,
                                                 const float* __restrict__ b,
                                                 const float* __restrict__ gamma,
                                                 const float* __restrict__ beta,
                                                 const float* __restrict__ mean,
                                                 const float* __restrict__ var,
                                                 float* __restrict__ out) {
    int t = blockIdx.x * blockDim.x + threadIdx.x;
    int lane = t & 31;
    int n = t >> 5;
    if (n >= NN) return;
    const float4* hl4 = (const float4*)hl;
    float di = dinv[n];
    float4 self = hl4[(size_t)n * 32 + lane];
    float4 bb = ((const float4*)b)[lane];
    float dsq = di * di;
    float4 acc;
    acc.x = fmaf(self.x, dsq, bb.x);
    acc.y = fmaf(self.y, dsq, bb.y);
    acc.z = fmaf(self.z, dsq, bb.z);
    acc.w = fmaf(self.w, dsq, bb.w);
    int e0 = rs[n], e1 = rs[n + 1];
    int e = e0;
    for (; e + 1 < e1; e += 2) {
        int s0 = esrc[e], s1 = esrc[e + 1];
        float w0 = ewt[e], w1 = ewt[e + 1];
        float4 v0 = hl4[(size_t)s0 * 32 + lane];
        float4 v1 = hl4[(size_t)s1 * 32 + lane];
        acc.x = fmaf(v0.x, w0, acc.x); acc.y = fmaf(v0.y, w0, acc.y);
        acc.z = fmaf(v0.z, w0, acc.z); acc.w = fmaf(v0.w, w0, acc.w);
        acc.x = fmaf(v1.x, w1, acc.x); acc.y = fmaf(v1.y, w1, acc.y);
        acc.z = fmaf(v1.z, w1, acc.z); acc.w = fmaf(v1.w, w1, acc.w);
    }
    if (e < e1) {
        int s0 = esrc[e];
        float w0 = ewt[e];
        float4 v0 = hl4[(size_t)s0 * 32 + lane];
        acc.x = fmaf(v0.x, w0, acc.x); acc.y = fmaf(v0.y, w0, acc.y);
        acc.z = fmaf(v0.z, w0, acc.z); acc.w = fmaf(v0.w, w0, acc.w);
    }
    float4 ga = ((const float4*)gamma)[lane];
    float4 be = ((const float4*)beta)[lane];
    float4 me = ((const float4*)mean)[lane];
    float4 va = ((const float4*)var)[lane];
    float4 o;
    o.x = fmaxf(fmaf(acc.x - me.x, ga.x * rsqrtf(va.x + BN_EPS), be.x), 0.f);
    o.y = fmaxf(fmaf(acc.y - me.y, ga.y * rsqrtf(va.y + BN_EPS), be.y), 0.f);
    o.z = fmaxf(fmaf(acc.z - me.z, ga.z * rsqrtf(va.z + BN_EPS), be.z), 0.f);
    o.w = fmaxf(fmaf(acc.w - me.w, ga.w * rsqrtf(va.w + BN_EPS), be.w), 0.f);
    ((float4*)out)[(size_t)n * 32 + lane] = o;
}

// ---------------- global mean pool (batch is sorted) ----------------
// 1024 threads = 32 node-rows x 32 float4-lanes; LDS tree reduction.

__global__ __launch_bounds__(1024) void pool_kernel(const float* __restrict__ h,
                                                    const int* __restrict__ batch,
                                                    float* __restrict__ lig) {
    int g = blockIdx.x;
    int lane = threadIdx.x & 31;   // float4 index within feature row
    int row = threadIdx.x >> 5;    // 0..31
    __shared__ int se[2];
    if (threadIdx.x < 2) {
        int target = g + threadIdx.x;
        int lo = 0, hi = NN;
        while (lo < hi) {
            int mid = (lo + hi) >> 1;
            if (batch[mid] < target) lo = mid + 1; else hi = mid;
        }
        se[threadIdx.x] = lo;
    }
    __syncthreads();
    int start = se[0], end = se[1];
    const float4* h4 = (const float4*)h;
    float4 acc = make_float4(0.f, 0.f, 0.f, 0.f);
    for (int n = start + row; n < end; n += 32) {
        float4 v = h4[(size_t)n * 32 + lane];
        acc.x += v.x; acc.y += v.y; acc.z += v.z; acc.w += v.w;
    }
    __shared__ float4 part[32][32];
    part[row][lane] = acc;
    __syncthreads();
#pragma unroll
    for (int off = 16; off >= 1; off >>= 1) {
        if (row < off) {
            float4 a = part[row][lane];
            float4 c = part[row + off][lane];
            a.x += c.x; a.y += c.y; a.z += c.z; a.w += c.w;
            part[row][lane] = a;
        }
        __syncthreads();
    }
    if (row == 0) {
        float inv = 1.0f / fmaxf((float)(end - start), 1.0f);
        float4 a = part[0][lane];
        a.x *= inv; a.y *= inv; a.z *= inv; a.w *= inv;
        ((float4*)lig)[g * 32 + lane] = a;
    }
}

// ---------------- pocket MLP: 28 -> 64 -> 64 ----------------

__global__ __launch_bounds__(64) void pocket_kernel(const float* __restrict__ pocket,
                                                    const float* __restrict__ pw1,
                                                    const float* __restrict__ pb1,
                                                    const float* __restrict__ pw2,
                                                    const float* __restrict__ pb2,
                                                    float* __restrict__ p) {
    int j = threadIdx.x;
    __shared__ float t1[64];
    float acc = pb1[j];
    for (int k = 0; k < 28; k++) acc = fmaf(pocket[k], pw1[k * 64 + j], acc);
    t1[j] = fmaxf(acc, 0.f);
    __syncthreads();
    float acc2 = pb2[j];
    for (int k = 0; k < 64; k++) acc2 = fmaf(t1[k], pw2[k * 64 + j], acc2);
    p[j] = acc2;
}

// ---------------- classifier: concat(lig, p) -> 96 -> 1 ----------------

__global__ __launch_bounds__(96) void cls_kernel(const float* __restrict__ lig,
                                                 const float* __restrict__ p,
                                                 const float* __restrict__ cw1,
                                                 const float* __restrict__ cb1,
                                                 const float* __restrict__ cw2,
                                                 const float* __restrict__ cb2,
                                                 float* __restrict__ out) {
    int g = blockIdx.x;
    int j = threadIdx.x;
    __shared__ float emb[192];
    __shared__ float hid[96];
    for (int k = j; k < HID; k += 96) emb[k] = lig[g * HID + k];
    for (int k = j; k < 64; k += 96) emb[HID + k] = p[k];
    __syncthreads();
    float acc = cb1[j];
    for (int k = 0; k < 192; k++) acc = fmaf(emb[k], cw1[k * 96 + j], acc);
    hid[j] = fmaxf(acc, 0.f) * cw2[j];
    __syncthreads();
    if (j == 0) {
        float s = cb2[0];
        for (int k = 0; k < 96; k++) s += hid[k];
        out[g] = s;
    }
}

extern "C" void kernel_launch(void* const* d_in, const int* in_sizes, int n_in,
                              void* d_out, int out_size, void* d_ws, size_t ws_size,
                              hipStream_t stream) {
    const float* x        = (const float*)d_in[0];
    const int*   eidx     = (const int*)d_in[1];
    const int*   batch    = (const int*)d_in[2];
    const float* pocket   = (const float*)d_in[3];
    const float* W0 = (const float*)d_in[4];
    const float* b0 = (const float*)d_in[5];
    const float* W1 = (const float*)d_in[6];
    const float* b1 = (const float*)d_in[7];
    const float* W2 = (const float*)d_in[8];
    const float* b2 = (const float*)d_in[9];
    const float* bn_gamma = (const float*)d_in[10];
    const float* bn_beta  = (const float*)d_in[11];
    const float* bn_mean  = (const float*)d_in[12];
    const float* bn_var   = (const float*)d_in[13];
    const float* pw1 = (const float*)d_in[14]; const float* pb1 = (const float*)d_in[15];
    const float* pw2 = (const float*)d_in[16]; const float* pb2 = (const float*)d_in[17];
    const float* cw1 = (const float*)d_in[18]; const float* cb1 = (const float*)d_in[19];
    const float* cw2 = (const float*)d_in[20]; const float* cb2 = (const float*)d_in[21];
    float* out = (float*)d_out;

    // Workspace layout (4-byte units, A/B 16B-aligned):
    float* ws   = (float*)d_ws;
    float* dinv = ws;                                   // NN
    int*   cnt  = (int*)(ws + NN);                      // NN (hist, then cursor)
    int*   rs   = cnt + NN;                             // NN+1
    int*   tsum = rs + NN + 1;                          // 128
    int*   esrc = tsum + 128;                           // NE
    float* ewt  = (float*)(esrc + NE);                  // NE
    float* xa   = ewt + NE;                             // NN*8
    size_t head = (size_t)NN * 2 + (NN + 1) + 128 + (size_t)NE * 2 + (size_t)NN * 8;
    head = (head + 3) & ~(size_t)3;                     // 16B align
    float* A    = ws + head;                            // NN*HID
    float* B    = A + (size_t)NN * HID;                 // NN*HID
    float* lig  = B + (size_t)NN * HID;                 // NG*HID
    float* pv   = lig + (size_t)NG * HID;               // 64

    const int* srcp = eidx;
    const int* dstp = eidx + NE;

    // ---- build CSR (by dst) + dinv + edge weights ----
    hipMemsetAsync(cnt, 0, NN * sizeof(int), stream);
    hist_kernel<<<(NE + 255) / 256, 256, 0, stream>>>(dstp, cnt);
    dinv_kernel<<<(NN + 255) / 256, 256, 0, stream>>>(cnt, dinv);
    scan_a<<<NTILES, 256, 0, stream>>>(cnt, rs, tsum);
    scan_b<<<1, 128, 0, stream>>>(tsum);
    scan_c<<<NTILES, 256, 0, stream>>>(rs, tsum, cnt);  // cnt becomes cursor
    bucket_kernel<<<(NE + 255) / 256, 256, 0, stream>>>(srcp, dstp, dinv, cnt, esrc, ewt);

    // ---- layer 0: aggregate x, then transform (A = relu(bn(agg(x) @ W0 + b0))) ----
    xagg_kernel<<<(NN * 8 + 255) / 256, 256, 0, stream>>>(x, rs, esrc, ewt, dinv, xa);
    l0_transform<<<2048, 256, 0, stream>>>(xa, W0, b0,
                                           bn_gamma + 0 * HID, bn_beta + 0 * HID,
                                           bn_mean + 0 * HID, bn_var + 0 * HID, A);
    // ---- layer 1 ----
    gcn_mm128<<<2048, 256, 0, stream>>>(A, W1, B);
    gather_bn<<<(NN * 32 + 255) / 256, 256, 0, stream>>>(B, rs, esrc, ewt, dinv, b1,
                                                         bn_gamma + 1 * HID, bn_beta + 1 * HID,
                                                         bn_mean + 1 * HID, bn_var + 1 * HID, A);
    // ---- layer 2 ----
    gcn_mm128<<<2048, 256, 0, stream>>>(A, W2, B);
    gather_bn<<<(NN * 32 + 255) / 256, 256, 0, stream>>>(B, rs, esrc, ewt, dinv, b2,
                                                         bn_gamma + 2 * HID, bn_beta + 2 * HID,
                                                         bn_mean + 2 * HID, bn_var + 2 * HID, A);

    // pool -> lig
    pool_kernel<<<NG, 1024, 0, stream>>>(A, batch, lig);
    // pocket MLP
    pocket_kernel<<<1, 64, 0, stream>>>(pocket, pw1, pb1, pw2, pb2, pv);
    // classifier
    cls_kernel<<<NG, 96, 0, stream>>>(lig, pv, cw1, cb1, cw2, cb2, out);
}